// Round 6
// baseline (184.502 us; speedup 1.0000x reference)
//
#include <hip/hip_runtime.h>
#include <stdint.h>

// Problem constants (fixed by the harness)
#define NB 8
#define NN 8192
#define NE 128
#define NH 8
#define NHD 16
#define NKH 32
#define NFF 128
#define NG 32
#define NM 1024          // NG*NG
#define NP 32
#define NT 8192          // NB*NM
#define NPTS 65536       // NB*NN

typedef __attribute__((ext_vector_type(8))) short bf16x8_t;
typedef __attribute__((ext_vector_type(4))) float f32x4_t;

// ---- workspace layout (bytes) ----
#define WS_MM      0         // 4 f32 (mn0,mn1,mx0,mx1) written by k_binkv block 0
#define WS_D0      64        // 8 f32: grid-token dots (q.kg/4 + kb0)
#define WS_Q       128       // 128 f32
#define WS_VG      640       // 128 f32
#define WS_PART    1152      // 32 x float4 min/max partials
#define WS_CNT     2048      // 8192 i32 -> ends 34816
#define WS_WVT     34816     // 128*128 ushort (bf16), [n][k] = WvT -> 67584
#define WS_WOT     67584     // 128*128 ushort -> 100352
#define WS_FW1T    100352    // 128*128 ushort -> 133120
#define WS_FW2T    133120    // 128*128 ushort -> 165888
#define WS_WKQT    165888    // 16*128 ushort: rows 0..7 = wkqh^T, 8..15 = 0 -> 169984
#define WS_XD      169984    // 262144 * 8  B: dense per-slot x (float2)  -> 2267136
#define WS_SD      2267136   // 262144 * 32 B: dense per-slot scores [8]f32 -> 10655744
#define WS_VD      10655744  // 262144 * 256 B: dense per-slot v rows (128 bf16) -> ~78 MB

__device__ __forceinline__ unsigned short f2bf(float f) {  // RNE
    unsigned u = __float_as_uint(f);
    u += 0x7FFFu + ((u >> 16) & 1u);
    return (unsigned short)(u >> 16);
}
__device__ __forceinline__ float bflo(unsigned w) { return __uint_as_float(w << 16); }
__device__ __forceinline__ float bfhi(unsigned w) { return __uint_as_float(w & 0xFFFF0000u); }

// ---------------- K_setup: tile-transpose pack + init + precompute + minmax ----------------
__global__ __launch_bounds__(256) void k_setup(
        const float* __restrict__ x,
        const float* __restrict__ Wk, const float* __restrict__ Wv, const float* __restrict__ Wo,
        const float* __restrict__ fW1, const float* __restrict__ fW2,
        const float* __restrict__ latent, const float* __restrict__ Wq,
        const float* __restrict__ lnq_g, const float* __restrict__ lnq_b,
        const float* __restrict__ lnk_g, const float* __restrict__ lnk_b,
        const float* __restrict__ kb1, const float* __restrict__ kW2, const float* __restrict__ kb2,
        int* __restrict__ cnt,
        unsigned short* __restrict__ WvT, unsigned short* __restrict__ WoT,
        unsigned short* __restrict__ fW1T, unsigned short* __restrict__ fW2T,
        float* __restrict__ ws_q, float* __restrict__ ws_vg, float* __restrict__ ws_d0,
        unsigned short* __restrict__ WkqT,
        float4* __restrict__ part) {
    int blk = blockIdx.x;
    int t = threadIdx.x;
    if (blk < 16) {
        __shared__ float s_t[64][65];
        const float* src; unsigned short* dst;
        int n0, k0;
        if (blk < 4) {
            int tn = blk >> 1, tk = blk & 1;
            n0 = tn * 64; k0 = tk * 64;
            src = Wv; dst = WvT;
        } else {
            int m = (blk - 4) >> 2, s4 = (blk - 4) & 3;
            int tn = s4 >> 1, tk = s4 & 1;
            n0 = tn * 64; k0 = tk * 64;
            src = (m == 0) ? Wo : (m == 1) ? fW1 : fW2;
            dst = (m == 0) ? WoT : (m == 1) ? fW1T : fW2T;
        }
        int tx = t & 63, ty = t >> 6;
        #pragma unroll
        for (int r = 0; r < 16; ++r) {
            int kr = r * 4 + ty;
            s_t[kr][tx] = src[(k0 + kr) * 128 + n0 + tx];
        }
        __syncthreads();
        #pragma unroll
        for (int r = 0; r < 16; ++r) {
            int nr = r * 4 + ty;
            dst[(n0 + nr) * 128 + k0 + tx] = f2bf(s_t[tx][nr]);
        }
    } else if (blk < 48) {
        int idx = (blk - 16) * 256 + t;   // exactly 8192
        cnt[idx] = 0;
    } else if (blk == 48) {
        __shared__ float s_qn[128], s_kn[128], s_q[128], s_kg[128];
        __shared__ float s_mu, s_rstd;
        if (t < 64) {
            float v0 = latent[t], v1 = latent[t + 64];
            float s = v0 + v1;
            for (int m = 32; m > 0; m >>= 1) s += __shfl_xor(s, m);
            float mu = s * (1.0f / 128.0f);
            float d0 = v0 - mu, d1 = v1 - mu;
            float q = d0 * d0 + d1 * d1;
            for (int m = 32; m > 0; m >>= 1) q += __shfl_xor(q, m);
            if (t == 0) { s_mu = mu; s_rstd = rsqrtf(q * (1.0f / 128.0f) + 1e-5f); }
        }
        __syncthreads();
        if (t < 128) {
            float nv = (latent[t] - s_mu) * s_rstd;
            s_qn[t] = nv * lnq_g[t] + lnq_b[t];
            s_kn[t] = nv * lnk_g[t] + lnk_b[t];
        }
        __syncthreads();
        if (t < 128) {
            float aq = 0.f, ak = 0.f, av = 0.f;
            for (int e = 0; e < 128; ++e) {
                aq += s_qn[e] * Wq[e * 128 + t];
                ak += s_kn[e] * Wk[e * 128 + t];
                av += s_kn[e] * Wv[e * 128 + t];
            }
            s_q[t] = aq; s_kg[t] = ak;
            ws_q[t] = aq; ws_vg[t] = av;
        }
        __syncthreads();
        if (t < 128) {
            // WkqT[h][e] = bf16(0.25 * sum_d Wk[e][h*16+d] * q[h*16+d]); rows 8..15 zero.
            const float* wr = Wk + t * 128;   // input-dim row e = t
            #pragma unroll
            for (int h = 0; h < 8; ++h) {
                float a = 0.f;
                #pragma unroll
                for (int d = 0; d < 16; ++d) a += wr[h * 16 + d] * s_q[h * 16 + d];
                WkqT[h * 128 + t] = f2bf(a * 0.25f);
                WkqT[(h + 8) * 128 + t] = 0;
            }
        }
        if (t < 8) {
            float acc = 0.f;
            for (int d = 0; d < 16; ++d) acc += s_q[t * 16 + d] * s_kg[t * 16 + d];
            float kb0 = kb2[t];
            for (int j = 0; j < 32; ++j) kb0 += fmaxf(kb1[j], 0.f) * kW2[j * 8 + t];
            ws_d0[t] = acc * 0.25f + kb0;
        }
    } else {
        __shared__ float s_red[4][4];
        int pb = blk - 49;                 // 0..31
        const float4* xp = (const float4*)x + pb * 1024;
        float mn0 = 1e30f, mx0 = -1e30f, mn1 = 1e30f, mx1 = -1e30f;
        #pragma unroll
        for (int it = 0; it < 4; ++it) {
            float4 v = xp[it * 256 + t];    // two points: (x,y),(z,w)
            mn0 = fminf(mn0, fminf(v.x, v.z)); mx0 = fmaxf(mx0, fmaxf(v.x, v.z));
            mn1 = fminf(mn1, fminf(v.y, v.w)); mx1 = fmaxf(mx1, fmaxf(v.y, v.w));
        }
        #pragma unroll
        for (int m = 32; m > 0; m >>= 1) {
            mn0 = fminf(mn0, __shfl_xor(mn0, m)); mx0 = fmaxf(mx0, __shfl_xor(mx0, m));
            mn1 = fminf(mn1, __shfl_xor(mn1, m)); mx1 = fmaxf(mx1, __shfl_xor(mx1, m));
        }
        int w = t >> 6;
        if ((t & 63) == 0) {
            s_red[w][0] = mn0; s_red[w][1] = mn1; s_red[w][2] = mx0; s_red[w][3] = mx1;
        }
        __syncthreads();
        if (t == 0) {
            float a0 = fminf(fminf(s_red[0][0], s_red[1][0]), fminf(s_red[2][0], s_red[3][0]));
            float a1 = fminf(fminf(s_red[0][1], s_red[1][1]), fminf(s_red[2][1], s_red[3][1]));
            float b0 = fmaxf(fmaxf(s_red[0][2], s_red[1][2]), fmaxf(s_red[2][2], s_red[3][2]));
            float b1 = fmaxf(fmaxf(s_red[0][3], s_red[1][3]), fmaxf(s_red[2][3], s_red[3][3]));
            part[pb] = make_float4(a0, a1, b0, b1);
        }
    }
}

// ---------------- K2: v-projection + binning + DENSE SCATTER of v/scores/x
//                     (1024 blocks, 64 tokens each; no separate binning pass) ----------------
__global__ __launch_bounds__(256) void k_binkv(
        const float* __restrict__ x, const float* __restrict__ z,
        const float4* __restrict__ part, float* __restrict__ mm,
        const float* __restrict__ lnk_g, const float* __restrict__ lnk_b,
        const unsigned short* __restrict__ WkqT,
        const float* __restrict__ kW1, const float* __restrict__ kb1,
        const float* __restrict__ kW2, const float* __restrict__ kb2,
        const unsigned short* __restrict__ WvT,
        unsigned short* __restrict__ vd, float* __restrict__ sd, float2* __restrict__ xd,
        int* __restrict__ cnt) {
    __shared__ unsigned short s_zn[64][136];
    __shared__ unsigned short s_stage[4][16][68];
    __shared__ int s_dsl[64];                    // dense slot index per token (-1 = dropped)
    int t = threadIdx.x;
    int w = t >> 6, lane = t & 63;
    long base = (long)blockIdx.x * 64;
    int sub = lane >> 5;
    int lq = lane & 31;
    int mrow = lane & 15, quad = lane >> 4;

    // mm reduce from part[] (written by k_setup)
    float mn0 = 1e30f, mn1 = 1e30f, mx0 = -1e30f, mx1 = -1e30f;
    if (lane < 32) { float4 p = part[lane]; mn0 = p.x; mn1 = p.y; mx0 = p.z; mx1 = p.w; }
    #pragma unroll
    for (int m = 32; m > 0; m >>= 1) {
        mn0 = fminf(mn0, __shfl_xor(mn0, m)); mx0 = fmaxf(mx0, __shfl_xor(mx0, m));
        mn1 = fminf(mn1, __shfl_xor(mn1, m)); mx1 = fmaxf(mx1, __shfl_xor(mx1, m));
    }
    if (blockIdx.x == 0 && t == 0) {
        mm[0] = mn0; mm[1] = mn1; mm[2] = mx0; mm[3] = mx1;
    }
    // early x load (4 lanes per point share an address -> broadcast)
    int ptl = w * 16 + mrow;
    float2 xv2 = ((const float2*)x)[base + ptl];

    // wave (th, fh): tokens th*32..th*32+31, v-features fh*64..fh*64+63
    int th = w >> 1, fh = w & 1;
    bf16x8_t afrag[4][4];
    #pragma unroll
    for (int j = 0; j < 4; ++j) {
        const unsigned short* ap = WvT + ((fh * 4 + j) * 16 + mrow) * 128 + quad * 8;
        #pragma unroll
        for (int kc = 0; kc < 4; ++kc)
            afrag[j][kc] = *(const bf16x8_t*)(ap + kc * 32);
    }
    // score-tile A fragment (wkqh^T, rows 0..7 = heads, 8..15 = 0)
    bf16x8_t sfrag[4];
    #pragma unroll
    for (int kc = 0; kc < 4; ++kc)
        sfrag[kc] = *(const bf16x8_t*)(WkqT + mrow * 128 + kc * 32 + quad * 8);

    // LN: 2 rows/iter, 32 lanes/row, hoisted loads
    float4 g4 = ((const float4*)lnk_g)[lq];
    float4 b4 = ((const float4*)lnk_b)[lq];
    float4 v[8];
    #pragma unroll
    for (int i = 0; i < 8; ++i) {
        int pl = w * 16 + i * 2 + sub;
        v[i] = ((const float4*)z)[(base + pl) * 32 + lq];
    }
    #pragma unroll
    for (int i = 0; i < 8; ++i) {
        int pl = w * 16 + i * 2 + sub;
        float sum = v[i].x + v[i].y + v[i].z + v[i].w;
        float ssq = v[i].x * v[i].x + v[i].y * v[i].y + v[i].z * v[i].z + v[i].w * v[i].w;
        #pragma unroll
        for (int m = 1; m < 32; m <<= 1) {
            sum += __shfl_xor(sum, m);
            ssq += __shfl_xor(ssq, m);
        }
        float mu = sum * (1.0f / 128.0f);
        float var = fmaxf(ssq * (1.0f / 128.0f) - mu * mu, 0.0f);
        float rstd = rsqrtf(var + 1e-5f);
        float n0 = (v[i].x - mu) * rstd * g4.x + b4.x;
        float n1 = (v[i].y - mu) * rstd * g4.y + b4.y;
        float n2 = (v[i].z - mu) * rstd * g4.z + b4.z;
        float n3 = (v[i].w - mu) * rstd * g4.w + b4.w;
        unsigned d0 = (unsigned)f2bf(n0) | ((unsigned)f2bf(n1) << 16);
        unsigned d1 = (unsigned)f2bf(n2) | ((unsigned)f2bf(n3) << 16);
        *(uint2*)&s_zn[pl][lq * 4] = make_uint2(d0, d1);
    }

    // ---- binning for this wave's 16 tokens: quad-0 lane of each token atomics a slot ----
    float st0 = (mx0 - mn0) / 31.0f, st1 = (mx1 - mn1) / 31.0f;
    int i0 = (int)rintf((xv2.x - mn0) / st0); i0 = min(max(i0, 0), 31);
    int i1 = (int)rintf((xv2.y - mn1) / st1); i1 = min(max(i1, 0), 31);
    if (quad == 0) {
        long gi = base + ptl;
        int bb = (int)(gi >> 13);
        int cellc = (bb << 10) + i0 * 32 + i1;
        int slot = atomicAdd(&cnt[cellc], 1);
        s_dsl[ptl] = (slot < NP) ? ((cellc << 5) + slot) : -1;
    }
    __syncthreads();   // s_zn + s_dsl visible to all waves

    // ---- v-projection MFMA; burst-scatter 128B half-rows into dense vd ----
    #pragma unroll
    for (int tau = 0; tau < 2; ++tau) {
        int trow = th * 32 + tau * 16;
        bf16x8_t bfrag[4];
        #pragma unroll
        for (int kc = 0; kc < 4; ++kc)
            bfrag[kc] = *(const bf16x8_t*)&s_zn[trow + mrow][kc * 32 + quad * 8];
        #pragma unroll
        for (int j = 0; j < 4; ++j) {
            f32x4_t acc = {0.f, 0.f, 0.f, 0.f};
            #pragma unroll
            for (int kc = 0; kc < 4; ++kc)
                acc = __builtin_amdgcn_mfma_f32_16x16x32_bf16(afrag[j][kc], bfrag[kc], acc, 0, 0, 0);
            unsigned d0 = (unsigned)f2bf(acc[0]) | ((unsigned)f2bf(acc[1]) << 16);
            unsigned d1 = (unsigned)f2bf(acc[2]) | ((unsigned)f2bf(acc[3]) << 16);
            *(uint2*)&s_stage[w][mrow][j * 16 + quad * 4] = make_uint2(d0, d1);
        }
        int tok = lane >> 3, u = lane & 7;
        int dsA = s_dsl[trow + tok];
        int dsB = s_dsl[trow + tok + 8];
        uint4 ra = *(const uint4*)&s_stage[w][tok][u * 8];
        uint4 rb = *(const uint4*)&s_stage[w][tok + 8][u * 8];
        if (dsA >= 0) *(uint4*)(vd + (size_t)dsA * 128 + fh * 64 + u * 8) = ra;
        if (dsB >= 0) *(uint4*)(vd + (size_t)dsB * 128 + fh * 64 + u * 8) = rb;
    }

    // ---- per-head qk for this wave's kb tokens (tile w): D[row=head][col=token] ----
    f32x4_t sacc = {0.f, 0.f, 0.f, 0.f};
    {
        bf16x8_t sb[4];
        #pragma unroll
        for (int kc = 0; kc < 4; ++kc)
            sb[kc] = *(const bf16x8_t*)&s_zn[w * 16 + mrow][kc * 32 + quad * 8];
        #pragma unroll
        for (int kc = 0; kc < 4; ++kc)
            sacc = __builtin_amdgcn_mfma_f32_16x16x32_bf16(sfrag[kc], sb[kc], sacc, 0, 0, 0);
        // quad 0 lanes hold heads 0..3 (rows 0..3), quad 1 holds heads 4..7; quads 2,3 garbage
    }

    // ---- per-point kernel-bias MLP + dense score/x scatter (4 lanes per point) ----
    {
        float cx0 = (i0 == 31) ? mx0 : mn0 + i0 * st0;
        float cx1 = (i1 == 31) ? mx1 : mn1 + i1 * st1;
        float d0 = xv2.x - cx0, d1 = xv2.y - cx1;
        float k0 = 0.f, k1 = 0.f, k2 = 0.f, k3 = 0.f, k4 = 0.f, k5 = 0.f, k6 = 0.f, k7 = 0.f;
        #pragma unroll
        for (int jj = 0; jj < 8; ++jj) {
            int j = quad * 8 + jj;
            float hj = fmaf(d0, kW1[j], fmaf(d1, kW1[32 + j], kb1[j]));
            hj = fmaxf(hj, 0.f);
            float4 w2a = *(const float4*)(kW2 + j * 8);
            float4 w2b = *(const float4*)(kW2 + j * 8 + 4);
            k0 = fmaf(hj, w2a.x, k0); k1 = fmaf(hj, w2a.y, k1);
            k2 = fmaf(hj, w2a.z, k2); k3 = fmaf(hj, w2a.w, k3);
            k4 = fmaf(hj, w2b.x, k4); k5 = fmaf(hj, w2b.y, k5);
            k6 = fmaf(hj, w2b.z, k6); k7 = fmaf(hj, w2b.w, k7);
        }
        k0 += __shfl_xor(k0, 16); k0 += __shfl_xor(k0, 32);
        k1 += __shfl_xor(k1, 16); k1 += __shfl_xor(k1, 32);
        k2 += __shfl_xor(k2, 16); k2 += __shfl_xor(k2, 32);
        k3 += __shfl_xor(k3, 16); k3 += __shfl_xor(k3, 32);
        k4 += __shfl_xor(k4, 16); k4 += __shfl_xor(k4, 32);
        k5 += __shfl_xor(k5, 16); k5 += __shfl_xor(k5, 32);
        k6 += __shfl_xor(k6, 16); k6 += __shfl_xor(k6, 32);
        k7 += __shfl_xor(k7, 16); k7 += __shfl_xor(k7, 32);
        int dslv = s_dsl[ptl];
        if (dslv >= 0) {
            if (quad == 0) {
                float4 kb2v = ((const float4*)kb2)[0];
                float4 o;
                o.x = sacc[0] + k0 + kb2v.x; o.y = sacc[1] + k1 + kb2v.y;
                o.z = sacc[2] + k2 + kb2v.z; o.w = sacc[3] + k3 + kb2v.w;
                *(float4*)(sd + (size_t)dslv * 8) = o;
            } else if (quad == 1) {
                float4 kb2v = ((const float4*)kb2)[1];
                float4 o;
                o.x = sacc[0] + k4 + kb2v.x; o.y = sacc[1] + k5 + kb2v.y;
                o.z = sacc[2] + k6 + kb2v.z; o.w = sacc[3] + k7 + kb2v.w;
                *(float4*)(sd + (size_t)dslv * 8 + 4) = o;
            } else if (quad == 2) {
                xd[dslv] = xv2;
            }
        }
    }
}

// ---------------- K3: per-cell attention over DENSE per-cell records (zero indirection)
//                     + fused FFN on the block's 4 tokens ----------------
__global__ __launch_bounds__(256) void k_attn(
        const int* __restrict__ cnt, const float* __restrict__ mm,
        const unsigned short* __restrict__ vd, const float* __restrict__ sd,
        const float2* __restrict__ xd,
        const float* __restrict__ ws_vg, const float* __restrict__ ws_d0,
        const float* __restrict__ latent, const float* __restrict__ bo,
        const float* __restrict__ ln2_g, const float* __restrict__ ln2_b,
        const float* __restrict__ fb1, const float* __restrict__ fb2,
        const unsigned short* __restrict__ WoT, const unsigned short* __restrict__ fW1T,
        const unsigned short* __restrict__ fW2T,
        float* __restrict__ xout, float* __restrict__ zout) {
    __shared__ unsigned short s_a[16][136];   // rows 0..3 = attn out / h1; 4..15 garbage (padded M)
    __shared__ unsigned short s_a2[16][136];  // rows 0..3 = LN2 out
    __shared__ float s_z[4][128];
    __shared__ float s_lat[128], s_g2[128], s_b2[128], s_fb1v[128], s_fb2v[128];
    int t = threadIdx.x;
    int l = t & 63;
    int w = t >> 6;
    int bm = blockIdx.x * 4 + w;   // one wave per (b,cell) token
    int h = l >> 3, jp = l & 7;

    int craw = cnt[bm];            // independent queue; masks only, not addresses
    if (t < 128) {
        s_lat[t] = latent[t] + bo[t];
        s_g2[t] = ln2_g[t]; s_b2[t] = ln2_b[t];
        s_fb1v[t] = fb1[t]; s_fb2v[t] = fb2[t];
    }

    size_t db = (size_t)bm << 5;   // dense slot base = bm*32

    // ---- all addresses affine in bm: issue everything immediately ----
    float scv[4];
    float2 xv4[4];
    #pragma unroll
    for (int g = 0; g < 4; ++g) {
        scv[g] = sd[(db + g * 8 + jp) * 8 + h];   // 256B coalesced per g
        xv4[g] = xd[db + g * 8 + jp];             // broadcast across h-groups
    }
    unsigned vreg[16];
    const unsigned* vrow = (const unsigned*)vd + db * 64;   // 64 dwords per slot row
    #pragma unroll
    for (int k = 0; k < 8; ++k) vreg[k] = vrow[(size_t)k * 64 + l];

    int c = min(craw, NP);
    #pragma unroll
    for (int k = 0; k < 8; ++k) vreg[k] = (k < c) ? vreg[k] : 0u;   // poison -> 0
    if (c > 8) {
        #pragma unroll
        for (int k = 8; k < 16; ++k) {
            unsigned vw = vrow[(size_t)k * 64 + l];
            vreg[k] = (k < c) ? vw : 0u;
        }
    } else {
        #pragma unroll
        for (int k = 8; k < 16; ++k) vreg[k] = 0u;
    }

    float mn0 = mm[0], mn1 = mm[1], mx0 = mm[2], mx1 = mm[3];
    int i0 = (bm & 1023) >> 5, i1 = bm & 31;
    float st0 = (mx0 - mn0) / 31.0f, st1 = (mx1 - mn1) / 31.0f;
    float xg0 = (i0 == 31) ? mx0 : mn0 + i0 * st0;
    float xg1 = (i1 == 31) ? mx1 : mn1 + i1 * st1;
    float vg0 = ws_vg[2 * l], vg1 = ws_vg[2 * l + 1];
    float ag = ws_d0[h];

    // ---- per-head softmax over masked scores ----
    float areg[4];
    #pragma unroll
    for (int g = 0; g < 4; ++g)
        areg[g] = (g * 8 + jp < c) ? scv[g] : -1e30f;

    float mx = fmaxf(fmaxf(areg[0], areg[1]), fmaxf(areg[2], areg[3]));
    mx = fmaxf(mx, ag);
    mx = fmaxf(mx, __shfl_xor(mx, 1));
    mx = fmaxf(mx, __shfl_xor(mx, 2));
    mx = fmaxf(mx, __shfl_xor(mx, 4));
    float e0 = __expf(areg[0] - mx), e1 = __expf(areg[1] - mx);
    float e2 = __expf(areg[2] - mx), e3 = __expf(areg[3] - mx);
    float eg = __expf(ag - mx);
    float s = e0 + e1 + e2 + e3;
    s += __shfl_xor(s, 1);
    s += __shfl_xor(s, 2);
    s += __shfl_xor(s, 4);
    s += eg;
    float inv = 1.0f / s;

    // ---- PV: slots 0..15 from registers; 16..31 rare wave-uniform path ----
    float accA = eg * inv * vg0, accB = eg * inv * vg1;
    #pragma unroll
    for (int k8 = 0; k8 < 8; ++k8) {
        int src = (l & 56) | k8;
        float a0 = __shfl(e0, src) * inv;
        float a1 = __shfl(e1, src) * inv;
        unsigned vw0 = vreg[k8], vw1 = vreg[8 + k8];
        accA = fmaf(a0, bflo(vw0), accA); accB = fmaf(a0, bfhi(vw0), accB);
        accA = fmaf(a1, bflo(vw1), accA); accB = fmaf(a1, bfhi(vw1), accB);
    }
    if (c > 16) {
        #pragma unroll
        for (int k8 = 0; k8 < 8; ++k8) {
            int key2 = 16 + k8, key3 = 24 + k8;
            unsigned vw2 = vrow[(size_t)key2 * 64 + l];
            unsigned vw3 = vrow[(size_t)key3 * 64 + l];
            vw2 = (key2 < c) ? vw2 : 0u;
            vw3 = (key3 < c) ? vw3 : 0u;
            int src = (l & 56) | k8;
            float a2 = __shfl(e2, src) * inv;
            float a3 = __shfl(e3, src) * inv;
            accA = fmaf(a2, bflo(vw2), accA); accB = fmaf(a2, bfhi(vw2), accB);
            accA = fmaf(a3, bflo(vw3), accA); accB = fmaf(a3, bfhi(vw3), accB);
        }
    }
    unsigned ow = ((unsigned)f2bf(accB) << 16) | (unsigned)f2bf(accA);
    *(unsigned*)&s_a[w][2 * l] = ow;   // row w = this wave's token; features 2l, 2l+1

    float s0 = e0 * inv, s1 = e1 * inv, s2 = e2 * inv, s3 = e3 * inv, sg = eg * inv;
    #pragma unroll
    for (int m = 8; m <= 32; m <<= 1) {
        s0 += __shfl_xor(s0, m); s1 += __shfl_xor(s1, m);
        s2 += __shfl_xor(s2, m); s3 += __shfl_xor(s3, m);
        sg += __shfl_xor(sg, m);
    }
    float px0 = 0.f, px1 = 0.f;
    {
        bool v0 = (jp < c), v1 = (8 + jp < c), v2 = (16 + jp < c), v3 = (24 + jp < c);
        px0 = fmaf(s0, v0 ? xv4[0].x : 0.f, px0);  px1 = fmaf(s0, v0 ? xv4[0].y : 0.f, px1);
        px0 = fmaf(s1, v1 ? xv4[1].x : 0.f, px0);  px1 = fmaf(s1, v1 ? xv4[1].y : 0.f, px1);
        px0 = fmaf(s2, v2 ? xv4[2].x : 0.f, px0);  px1 = fmaf(s2, v2 ? xv4[2].y : 0.f, px1);
        px0 = fmaf(s3, v3 ? xv4[3].x : 0.f, px0);  px1 = fmaf(s3, v3 ? xv4[3].y : 0.f, px1);
    }
    px0 += __shfl_xor(px0, 1); px1 += __shfl_xor(px1, 1);
    px0 += __shfl_xor(px0, 2); px1 += __shfl_xor(px1, 2);
    px0 += __shfl_xor(px0, 4); px1 += __shfl_xor(px1, 4);
    if (l == 0) {
        xout[bm * 2]     = (px0 + sg * xg0) * 0.125f;
        xout[bm * 2 + 1] = (px1 + sg * xg1) * 0.125f;
    }

    // ---------------- fused FFN on this block's 4 tokens ----------------
    __syncthreads();
    int mrow = l & 15, quad = l >> 4;
    int base4 = blockIdx.x * 4;
    { // GEMM1: attn_out @ Wo + (latent + bo) -> s_z rows 0..3
        bf16x8_t a[4];
        #pragma unroll
        for (int kc = 0; kc < 4; ++kc)
            a[kc] = *(const bf16x8_t*)&s_a[mrow][kc * 32 + quad * 8];
        #pragma unroll
        for (int cc = 0; cc < 2; ++cc) {
            int ct = w * 2 + cc;
            f32x4_t acc = {0.f, 0.f, 0.f, 0.f};
            const unsigned short* bp = WoT + (ct * 16 + mrow) * 128 + quad * 8;
            #pragma unroll
            for (int kc = 0; kc < 4; ++kc)
                acc = __builtin_amdgcn_mfma_f32_16x16x32_bf16(a[kc], *(const bf16x8_t*)(bp + kc * 32), acc, 0, 0, 0);
            if (quad == 0) {   // D rows = quad*4+r; only rows 0..3 are real tokens
                int f = ct * 16 + mrow;
                #pragma unroll
                for (int r = 0; r < 4; ++r) s_z[r][f] = acc[r] + s_lat[f];
            }
        }
    }
    __syncthreads();
    { // LN2: wave w normalizes row w
        float v0 = s_z[w][l], v1 = s_z[w][l + 64];
        float ssum = v0 + v1;
        #pragma unroll
        for (int m = 32; m > 0; m >>= 1) ssum += __shfl_xor(ssum, m);
        float mu = ssum * (1.0f / 128.0f);
        float d0 = v0 - mu, d1 = v1 - mu;
        float qq = d0 * d0 + d1 * d1;
        #pragma unroll
        for (int m = 32; m > 0; m >>= 1) qq += __shfl_xor(qq, m);
        float rstd = rsqrtf(qq * (1.0f / 128.0f) + 1e-5f);
        s_a2[w][l]      = f2bf(d0 * rstd * s_g2[l] + s_b2[l]);
        s_a2[w][l + 64] = f2bf(d1 * rstd * s_g2[l + 64] + s_b2[l + 64]);
    }
    __syncthreads();
    { // GEMM2: relu(LN2 @ fW1 + fb1) -> s_a rows 0..3 (reuse)
        bf16x8_t a[4];
        #pragma unroll
        for (int kc = 0; kc < 4; ++kc)
            a[kc] = *(const bf16x8_t*)&s_a2[mrow][kc * 32 + quad * 8];
        #pragma unroll
        for (int cc = 0; cc < 2; ++cc) {
            int ct = w * 2 + cc;
            f32x4_t acc = {0.f, 0.f, 0.f, 0.f};
            const unsigned short* bp = fW1T + (ct * 16 + mrow) * 128 + quad * 8;
            #pragma unroll
            for (int kc = 0; kc < 4; ++kc)
                acc = __builtin_amdgcn_mfma_f32_16x16x32_bf16(a[kc], *(const bf16x8_t*)(bp + kc * 32), acc, 0, 0, 0);
            if (quad == 0) {
                int f = ct * 16 + mrow;
                #pragma unroll
                for (int r = 0; r < 4; ++r)
                    s_a[r][f] = f2bf(fmaxf(acc[r] + s_fb1v[f], 0.f));
            }
        }
    }
    __syncthreads();
    { // GEMM3: z + h1 @ fW2 + fb2 -> zout (only real rows written)
        bf16x8_t a[4];
        #pragma unroll
        for (int kc = 0; kc < 4; ++kc)
            a[kc] = *(const bf16x8_t*)&s_a[mrow][kc * 32 + quad * 8];
        #pragma unroll
        for (int cc = 0; cc < 2; ++cc) {
            int ct = w * 2 + cc;
            f32x4_t acc = {0.f, 0.f, 0.f, 0.f};
            const unsigned short* bp = fW2T + (ct * 16 + mrow) * 128 + quad * 8;
            #pragma unroll
            for (int kc = 0; kc < 4; ++kc)
                acc = __builtin_amdgcn_mfma_f32_16x16x32_bf16(a[kc], *(const bf16x8_t*)(bp + kc * 32), acc, 0, 0, 0);
            if (quad == 0) {
                int f = ct * 16 + mrow;
                #pragma unroll
                for (int r = 0; r < 4; ++r)
                    zout[(base4 + r) * 128 + f] = s_z[r][f] + acc[r] + s_fb2v[f];
            }
        }
    }
}

extern "C" void kernel_launch(void* const* d_in, const int* in_sizes, int n_in,
                              void* d_out, int out_size, void* d_ws, size_t ws_size,
                              hipStream_t stream) {
    const float* x     = (const float*)d_in[0];
    const float* z     = (const float*)d_in[1];
    const float* latent= (const float*)d_in[6];
    const float* Wq    = (const float*)d_in[7];
    const float* Wk    = (const float*)d_in[8];
    const float* Wv    = (const float*)d_in[9];
    const float* Wo    = (const float*)d_in[10];
    const float* bo    = (const float*)d_in[11];
    const float* kW1   = (const float*)d_in[12];
    const float* kb1   = (const float*)d_in[13];
    const float* kW2   = (const float*)d_in[14];
    const float* kb2   = (const float*)d_in[15];
    const float* lnq_g = (const float*)d_in[16];
    const float* lnq_b = (const float*)d_in[17];
    const float* lnk_g = (const float*)d_in[18];
    const float* lnk_b = (const float*)d_in[19];
    const float* ln2_g = (const float*)d_in[20];
    const float* ln2_b = (const float*)d_in[21];
    const float* fW1   = (const float*)d_in[22];
    const float* fb1   = (const float*)d_in[23];
    const float* fW2   = (const float*)d_in[24];
    const float* fb2   = (const float*)d_in[25];

    uint8_t* ws = (uint8_t*)d_ws;
    float* mm     = (float*)(ws + WS_MM);
    float* ws_d0  = (float*)(ws + WS_D0);
    float* ws_q   = (float*)(ws + WS_Q);
    float* ws_vg  = (float*)(ws + WS_VG);
    float4* part  = (float4*)(ws + WS_PART);
    int* cnt      = (int*)(ws + WS_CNT);
    unsigned short* WvT  = (unsigned short*)(ws + WS_WVT);
    unsigned short* WoT  = (unsigned short*)(ws + WS_WOT);
    unsigned short* fW1T = (unsigned short*)(ws + WS_FW1T);
    unsigned short* fW2T = (unsigned short*)(ws + WS_FW2T);
    unsigned short* WkqT = (unsigned short*)(ws + WS_WKQT);
    float2* xd    = (float2*)(ws + WS_XD);
    float* sd     = (float*)(ws + WS_SD);
    unsigned short* vd = (unsigned short*)(ws + WS_VD);

    float* xout = (float*)d_out;            // [B,32,32,2]  = 16384
    float* zout = (float*)d_out + 16384;    // [B,32,32,128]

    k_setup <<<81,   256, 0, stream>>>(x, Wk, Wv, Wo, fW1, fW2, latent, Wq,
                                       lnq_g, lnq_b, lnk_g, lnk_b, kb1, kW2, kb2,
                                       cnt, WvT, WoT, fW1T, fW2T, ws_q, ws_vg, ws_d0,
                                       WkqT, part);
    k_binkv <<<1024, 256, 0, stream>>>(x, z, part, mm, lnk_g, lnk_b, WkqT,
                                       kW1, kb1, kW2, kb2, WvT,
                                       vd, sd, xd, cnt);
    k_attn  <<<2048, 256, 0, stream>>>(cnt, mm, vd, sd, xd,
                                       ws_vg, ws_d0,
                                       latent, bo, ln2_g, ln2_b, fb1, fb2,
                                       WoT, fW1T, fW2T, xout, zout);
}

// Round 7
// 170.704 us; speedup vs baseline: 1.0808x; 1.0808x over previous
//
#include <hip/hip_runtime.h>
#include <stdint.h>

// Problem constants (fixed by the harness)
#define NB 8
#define NN 8192
#define NE 128
#define NH 8
#define NHD 16
#define NKH 32
#define NFF 128
#define NG 32
#define NM 1024          // NG*NG
#define NP 32
#define NT 8192          // NB*NM
#define NPTS 65536       // NB*NN

typedef __attribute__((ext_vector_type(8))) short bf16x8_t;
typedef __attribute__((ext_vector_type(4))) float f32x4_t;

// ---- workspace layout (bytes) ----
#define WS_MM      0         // 4 f32 (mn0,mn1,mx0,mx1)
#define WS_D0      64        // 8 f32: grid-token dots (q.kg/4 + kb0)
#define WS_Q       128       // 128 f32
#define WS_VG      640       // 128 f32
#define WS_PART    1152      // 32 x float4 min/max partials
#define WS_CNT     2048      // 8192 i32
#define WS_CELL    34816     // 65536 i32
#define WS_PIDX    296960    // 8192*32 i32
#define WS_WVT     1345536   // 128*128 ushort (bf16), [n][k] = WvT
#define WS_WOT     1411072   // 128*128 ushort
#define WS_FW1T    1443840   // 128*128 ushort
#define WS_FW2T    1476608   // 128*128 ushort
#define WS_WKQT    1509376   // 16*128 ushort (bf16): rows 0..7 = wkqh^T, rows 8..15 = 0
#define WS_SCORES  1513472   // 65536*8 f32: per-point per-head scores (qk + kb + kb2)
#define WS_KV      4194304   // 65536*128 ushort: v-only rows (256B each)

__device__ __forceinline__ unsigned short f2bf(float f) {  // RNE
    unsigned u = __float_as_uint(f);
    u += 0x7FFFu + ((u >> 16) & 1u);
    return (unsigned short)(u >> 16);
}
__device__ __forceinline__ float bflo(unsigned w) { return __uint_as_float(w << 16); }
__device__ __forceinline__ float bfhi(unsigned w) { return __uint_as_float(w & 0xFFFF0000u); }

// ---------------- K_setup: tile-transpose pack + init + precompute + minmax ----------------
__global__ __launch_bounds__(256) void k_setup(
        const float* __restrict__ x,
        const float* __restrict__ Wk, const float* __restrict__ Wv, const float* __restrict__ Wo,
        const float* __restrict__ fW1, const float* __restrict__ fW2,
        const float* __restrict__ latent, const float* __restrict__ Wq,
        const float* __restrict__ lnq_g, const float* __restrict__ lnq_b,
        const float* __restrict__ lnk_g, const float* __restrict__ lnk_b,
        const float* __restrict__ kb1, const float* __restrict__ kW2, const float* __restrict__ kb2,
        int* __restrict__ cnt,
        unsigned short* __restrict__ WvT, unsigned short* __restrict__ WoT,
        unsigned short* __restrict__ fW1T, unsigned short* __restrict__ fW2T,
        float* __restrict__ ws_q, float* __restrict__ ws_vg, float* __restrict__ ws_d0,
        unsigned short* __restrict__ WkqT,
        float4* __restrict__ part) {
    int blk = blockIdx.x;
    int t = threadIdx.x;
    if (blk < 16) {
        __shared__ float s_t[64][65];
        const float* src; unsigned short* dst;
        int n0, k0;
        if (blk < 4) {
            int tn = blk >> 1, tk = blk & 1;
            n0 = tn * 64; k0 = tk * 64;
            src = Wv; dst = WvT;
        } else {
            int m = (blk - 4) >> 2, s4 = (blk - 4) & 3;
            int tn = s4 >> 1, tk = s4 & 1;
            n0 = tn * 64; k0 = tk * 64;
            src = (m == 0) ? Wo : (m == 1) ? fW1 : fW2;
            dst = (m == 0) ? WoT : (m == 1) ? fW1T : fW2T;
        }
        int tx = t & 63, ty = t >> 6;
        #pragma unroll
        for (int r = 0; r < 16; ++r) {
            int kr = r * 4 + ty;
            s_t[kr][tx] = src[(k0 + kr) * 128 + n0 + tx];
        }
        __syncthreads();
        #pragma unroll
        for (int r = 0; r < 16; ++r) {
            int nr = r * 4 + ty;
            dst[(n0 + nr) * 128 + k0 + tx] = f2bf(s_t[tx][nr]);
        }
    } else if (blk < 48) {
        int idx = (blk - 16) * 256 + t;   // exactly 8192
        cnt[idx] = 0;
    } else if (blk == 48) {
        __shared__ float s_qn[128], s_kn[128], s_q[128], s_kg[128];
        __shared__ float s_mu, s_rstd;
        if (t < 64) {
            float v0 = latent[t], v1 = latent[t + 64];
            float s = v0 + v1;
            for (int m = 32; m > 0; m >>= 1) s += __shfl_xor(s, m);
            float mu = s * (1.0f / 128.0f);
            float d0 = v0 - mu, d1 = v1 - mu;
            float q = d0 * d0 + d1 * d1;
            for (int m = 32; m > 0; m >>= 1) q += __shfl_xor(q, m);
            if (t == 0) { s_mu = mu; s_rstd = rsqrtf(q * (1.0f / 128.0f) + 1e-5f); }
        }
        __syncthreads();
        if (t < 128) {
            float nv = (latent[t] - s_mu) * s_rstd;
            s_qn[t] = nv * lnq_g[t] + lnq_b[t];
            s_kn[t] = nv * lnk_g[t] + lnk_b[t];
        }
        __syncthreads();
        if (t < 128) {
            float aq = 0.f, ak = 0.f, av = 0.f;
            for (int e = 0; e < 128; ++e) {
                aq += s_qn[e] * Wq[e * 128 + t];
                ak += s_kn[e] * Wk[e * 128 + t];
                av += s_kn[e] * Wv[e * 128 + t];
            }
            s_q[t] = aq; s_kg[t] = ak;
            ws_q[t] = aq; ws_vg[t] = av;
        }
        __syncthreads();
        if (t < 128) {
            // WkqT[h][e] = bf16(0.25 * sum_d Wk[e][h*16+d] * q[h*16+d]); rows 8..15 zero.
            const float* wr = Wk + t * 128;   // input-dim row e = t
            #pragma unroll
            for (int h = 0; h < 8; ++h) {
                float a = 0.f;
                #pragma unroll
                for (int d = 0; d < 16; ++d) a += wr[h * 16 + d] * s_q[h * 16 + d];
                WkqT[h * 128 + t] = f2bf(a * 0.25f);
                WkqT[(h + 8) * 128 + t] = 0;
            }
        }
        if (t < 8) {
            float acc = 0.f;
            for (int d = 0; d < 16; ++d) acc += s_q[t * 16 + d] * s_kg[t * 16 + d];
            float kb0 = kb2[t];
            for (int j = 0; j < 32; ++j) kb0 += fmaxf(kb1[j], 0.f) * kW2[j * 8 + t];
            ws_d0[t] = acc * 0.25f + kb0;
        }
    } else {
        __shared__ float s_red[4][4];
        int pb = blk - 49;                 // 0..31
        const float4* xp = (const float4*)x + pb * 1024;
        float mn0 = 1e30f, mx0 = -1e30f, mn1 = 1e30f, mx1 = -1e30f;
        #pragma unroll
        for (int it = 0; it < 4; ++it) {
            float4 v = xp[it * 256 + t];    // two points: (x,y),(z,w)
            mn0 = fminf(mn0, fminf(v.x, v.z)); mx0 = fmaxf(mx0, fmaxf(v.x, v.z));
            mn1 = fminf(mn1, fminf(v.y, v.w)); mx1 = fmaxf(mx1, fmaxf(v.y, v.w));
        }
        #pragma unroll
        for (int m = 32; m > 0; m >>= 1) {
            mn0 = fminf(mn0, __shfl_xor(mn0, m)); mx0 = fmaxf(mx0, __shfl_xor(mx0, m));
            mn1 = fminf(mn1, __shfl_xor(mn1, m)); mx1 = fmaxf(mx1, __shfl_xor(mx1, m));
        }
        int w = t >> 6;
        if ((t & 63) == 0) {
            s_red[w][0] = mn0; s_red[w][1] = mn1; s_red[w][2] = mx0; s_red[w][3] = mx1;
        }
        __syncthreads();
        if (t == 0) {
            float a0 = fminf(fminf(s_red[0][0], s_red[1][0]), fminf(s_red[2][0], s_red[3][0]));
            float a1 = fminf(fminf(s_red[0][1], s_red[1][1]), fminf(s_red[2][1], s_red[3][1]));
            float b0 = fmaxf(fmaxf(s_red[0][2], s_red[1][2]), fmaxf(s_red[2][2], s_red[3][2]));
            float b1 = fmaxf(fmaxf(s_red[0][3], s_red[1][3]), fmaxf(s_red[2][3], s_red[3][3]));
            part[pb] = make_float4(a0, a1, b0, b1);
        }
    }
}

// ---------------- K2: merged v-projection + per-point per-head score precompute
//                      (blocks 0..1023) + binning (blocks 1024..1279) ----------------
__global__ __launch_bounds__(256) void k_binkv(
        const float* __restrict__ x, const float* __restrict__ z,
        const float4* __restrict__ part, float* __restrict__ mm,
        const float* __restrict__ lnk_g, const float* __restrict__ lnk_b,
        const unsigned short* __restrict__ WkqT,
        const float* __restrict__ kW1, const float* __restrict__ kb1,
        const float* __restrict__ kW2, const float* __restrict__ kb2,
        const unsigned short* __restrict__ WvT, unsigned short* __restrict__ kv,
        float* __restrict__ scores,
        int* __restrict__ cell, int* __restrict__ cnt, int* __restrict__ ptIdx) {
    int t = threadIdx.x;
    if (blockIdx.x >= 1024) {
        // ---- binning path (256 blocks) ----
        int l = t & 63;
        float mn0 = 1e30f, mn1 = 1e30f, mx0 = -1e30f, mx1 = -1e30f;
        if (l < 32) { float4 p = part[l]; mn0 = p.x; mn1 = p.y; mx0 = p.z; mx1 = p.w; }
        #pragma unroll
        for (int m = 32; m > 0; m >>= 1) {
            mn0 = fminf(mn0, __shfl_xor(mn0, m)); mx0 = fmaxf(mx0, __shfl_xor(mx0, m));
            mn1 = fminf(mn1, __shfl_xor(mn1, m)); mx1 = fmaxf(mx1, __shfl_xor(mx1, m));
        }
        if (blockIdx.x == 1024 && t == 0) {
            mm[0] = mn0; mm[1] = mn1; mm[2] = mx0; mm[3] = mx1;
        }
        int i = (blockIdx.x - 1024) * 256 + t;  // 65536
        float st0 = (mx0 - mn0) / 31.0f, st1 = (mx1 - mn1) / 31.0f;  // matches jnp exactly
        float2 xv = ((const float2*)x)[i];
        int i0 = (int)rintf((xv.x - mn0) / st0); i0 = min(max(i0, 0), 31);
        int i1 = (int)rintf((xv.y - mn1) / st1); i1 = min(max(i1, 0), 31);
        int c = i0 * 32 + i1;
        cell[i] = c;
        int bb = i >> 13;
        int slot = atomicAdd(&cnt[bb * NM + c], 1);
        if (slot < NP) ptIdx[(bb * NM + c) * NP + slot] = i & (NN - 1);
        return;
    }
    // ---- kv path: 64 tokens per block; v-projection + per-point scores ----
    __shared__ unsigned short s_zn[64][136];
    __shared__ unsigned short s_stage[4][16][68];
    int w = t >> 6, lane = t & 63;
    long base = (long)blockIdx.x * 64;
    int sub = lane >> 5;
    int lq = lane & 31;
    int mrow = lane & 15, quad = lane >> 4;

    // mm reduce (needed for kb); part[] written by k_setup
    float mn0 = 1e30f, mn1 = 1e30f, mx0 = -1e30f, mx1 = -1e30f;
    if (lane < 32) { float4 p = part[lane]; mn0 = p.x; mn1 = p.y; mx0 = p.z; mx1 = p.w; }
    #pragma unroll
    for (int m = 32; m > 0; m >>= 1) {
        mn0 = fminf(mn0, __shfl_xor(mn0, m)); mx0 = fmaxf(mx0, __shfl_xor(mx0, m));
        mn1 = fminf(mn1, __shfl_xor(mn1, m)); mx1 = fmaxf(mx1, __shfl_xor(mx1, m));
    }
    // early x load for kb (4 lanes per point share an address -> broadcast)
    int ptl = w * 16 + mrow;
    float2 xv2 = ((const float2*)x)[base + ptl];

    // wave (th, fh): tokens th*32..th*32+31, v-features fh*64..fh*64+63
    int th = w >> 1, fh = w & 1;
    bf16x8_t afrag[4][4];
    #pragma unroll
    for (int j = 0; j < 4; ++j) {
        const unsigned short* ap = WvT + ((fh * 4 + j) * 16 + mrow) * 128 + quad * 8;
        #pragma unroll
        for (int kc = 0; kc < 4; ++kc)
            afrag[j][kc] = *(const bf16x8_t*)(ap + kc * 32);
    }
    // score-tile A fragment (wkqh^T, rows 0..7 = heads, 8..15 = 0)
    bf16x8_t sfrag[4];
    #pragma unroll
    for (int kc = 0; kc < 4; ++kc)
        sfrag[kc] = *(const bf16x8_t*)(WkqT + mrow * 128 + kc * 32 + quad * 8);

    // LN: 2 rows/iter, 32 lanes/row, hoisted loads
    float4 g4 = ((const float4*)lnk_g)[lq];
    float4 b4 = ((const float4*)lnk_b)[lq];
    float4 v[8];
    #pragma unroll
    for (int i = 0; i < 8; ++i) {
        int pl = w * 16 + i * 2 + sub;
        v[i] = ((const float4*)z)[(base + pl) * 32 + lq];
    }
    #pragma unroll
    for (int i = 0; i < 8; ++i) {
        int pl = w * 16 + i * 2 + sub;
        float sum = v[i].x + v[i].y + v[i].z + v[i].w;
        float ssq = v[i].x * v[i].x + v[i].y * v[i].y + v[i].z * v[i].z + v[i].w * v[i].w;
        #pragma unroll
        for (int m = 1; m < 32; m <<= 1) {
            sum += __shfl_xor(sum, m);
            ssq += __shfl_xor(ssq, m);
        }
        float mu = sum * (1.0f / 128.0f);
        float var = fmaxf(ssq * (1.0f / 128.0f) - mu * mu, 0.0f);
        float rstd = rsqrtf(var + 1e-5f);
        float n0 = (v[i].x - mu) * rstd * g4.x + b4.x;
        float n1 = (v[i].y - mu) * rstd * g4.y + b4.y;
        float n2 = (v[i].z - mu) * rstd * g4.z + b4.z;
        float n3 = (v[i].w - mu) * rstd * g4.w + b4.w;
        unsigned d0 = (unsigned)f2bf(n0) | ((unsigned)f2bf(n1) << 16);
        unsigned d1 = (unsigned)f2bf(n2) | ((unsigned)f2bf(n3) << 16);
        *(uint2*)&s_zn[pl][lq * 4] = make_uint2(d0, d1);
    }
    __syncthreads();   // waves now consume all rows

    #pragma unroll
    for (int tau = 0; tau < 2; ++tau) {
        int trow = th * 32 + tau * 16;
        bf16x8_t bfrag[4];
        #pragma unroll
        for (int kc = 0; kc < 4; ++kc)
            bfrag[kc] = *(const bf16x8_t*)&s_zn[trow + mrow][kc * 32 + quad * 8];
        #pragma unroll
        for (int j = 0; j < 4; ++j) {
            f32x4_t acc = {0.f, 0.f, 0.f, 0.f};
            #pragma unroll
            for (int kc = 0; kc < 4; ++kc)
                acc = __builtin_amdgcn_mfma_f32_16x16x32_bf16(afrag[j][kc], bfrag[kc], acc, 0, 0, 0);
            unsigned d0 = (unsigned)f2bf(acc[0]) | ((unsigned)f2bf(acc[1]) << 16);
            unsigned d1 = (unsigned)f2bf(acc[2]) | ((unsigned)f2bf(acc[3]) << 16);
            *(uint2*)&s_stage[w][mrow][j * 16 + quad * 4] = make_uint2(d0, d1);
        }
        int tok = lane >> 3, u = lane & 7;
        long tk0 = base + trow;
        uint4 ra = *(const uint4*)&s_stage[w][tok][u * 8];
        *(uint4*)(kv + (tk0 + tok) * 128 + fh * 64 + u * 8) = ra;
        uint4 rb = *(const uint4*)&s_stage[w][tok + 8][u * 8];
        *(uint4*)(kv + (tk0 + tok + 8) * 128 + fh * 64 + u * 8) = rb;
    }

    // ---- per-head qk for this wave's kb tokens (tile w): D[row=head][col=token] ----
    f32x4_t sacc = {0.f, 0.f, 0.f, 0.f};
    {
        bf16x8_t sb[4];
        #pragma unroll
        for (int kc = 0; kc < 4; ++kc)
            sb[kc] = *(const bf16x8_t*)&s_zn[w * 16 + mrow][kc * 32 + quad * 8];
        #pragma unroll
        for (int kc = 0; kc < 4; ++kc)
            sacc = __builtin_amdgcn_mfma_f32_16x16x32_bf16(sfrag[kc], sb[kc], sacc, 0, 0, 0);
        // quad 0 lanes hold heads 0..3 (rows 0..3), quad 1 holds heads 4..7; quads 2,3 garbage
    }

    // ---- per-point kernel-bias MLP + score store (4 lanes per point) ----
    {
        float st0 = (mx0 - mn0) / 31.0f, st1 = (mx1 - mn1) / 31.0f;
        int i0 = (int)rintf((xv2.x - mn0) / st0); i0 = min(max(i0, 0), 31);
        int i1 = (int)rintf((xv2.y - mn1) / st1); i1 = min(max(i1, 0), 31);
        float cx0 = (i0 == 31) ? mx0 : mn0 + i0 * st0;
        float cx1 = (i1 == 31) ? mx1 : mn1 + i1 * st1;
        float d0 = xv2.x - cx0, d1 = xv2.y - cx1;
        float k0 = 0.f, k1 = 0.f, k2 = 0.f, k3 = 0.f, k4 = 0.f, k5 = 0.f, k6 = 0.f, k7 = 0.f;
        #pragma unroll
        for (int jj = 0; jj < 8; ++jj) {
            int j = quad * 8 + jj;
            float hj = fmaf(d0, kW1[j], fmaf(d1, kW1[32 + j], kb1[j]));
            hj = fmaxf(hj, 0.f);
            float4 w2a = *(const float4*)(kW2 + j * 8);
            float4 w2b = *(const float4*)(kW2 + j * 8 + 4);
            k0 = fmaf(hj, w2a.x, k0); k1 = fmaf(hj, w2a.y, k1);
            k2 = fmaf(hj, w2a.z, k2); k3 = fmaf(hj, w2a.w, k3);
            k4 = fmaf(hj, w2b.x, k4); k5 = fmaf(hj, w2b.y, k5);
            k6 = fmaf(hj, w2b.z, k6); k7 = fmaf(hj, w2b.w, k7);
        }
        k0 += __shfl_xor(k0, 16); k0 += __shfl_xor(k0, 32);
        k1 += __shfl_xor(k1, 16); k1 += __shfl_xor(k1, 32);
        k2 += __shfl_xor(k2, 16); k2 += __shfl_xor(k2, 32);
        k3 += __shfl_xor(k3, 16); k3 += __shfl_xor(k3, 32);
        k4 += __shfl_xor(k4, 16); k4 += __shfl_xor(k4, 32);
        k5 += __shfl_xor(k5, 16); k5 += __shfl_xor(k5, 32);
        k6 += __shfl_xor(k6, 16); k6 += __shfl_xor(k6, 32);
        k7 += __shfl_xor(k7, 16); k7 += __shfl_xor(k7, 32);
        if (quad == 0) {
            // heads 0..3: qk = sacc[0..3] (D rows 0..3)
            float4 kb2v = ((const float4*)kb2)[0];
            float4 o;
            o.x = sacc[0] + k0 + kb2v.x; o.y = sacc[1] + k1 + kb2v.y;
            o.z = sacc[2] + k2 + kb2v.z; o.w = sacc[3] + k3 + kb2v.w;
            *(float4*)(scores + ((size_t)(base + ptl)) * 8) = o;
        } else if (quad == 1) {
            // heads 4..7: qk = sacc[0..3] (D rows 4..7)
            float4 kb2v = ((const float4*)kb2)[1];
            float4 o;
            o.x = sacc[0] + k4 + kb2v.x; o.y = sacc[1] + k5 + kb2v.y;
            o.z = sacc[2] + k6 + kb2v.z; o.w = sacc[3] + k7 + kb2v.w;
            *(float4*)(scores + ((size_t)(base + ptl)) * 8 + 4) = o;
        }
    }
}

// ---------------- K3: 16 tokens per block (4 per wave, unrolled) + single M=16 FFN
//                     with zero padding waste ----------------
__global__ __launch_bounds__(256) void k_attn(const float* __restrict__ x,
        const int* __restrict__ cell, const int* __restrict__ cnt, int* __restrict__ ptIdx,
        const float* __restrict__ mm, const unsigned short* __restrict__ kv,
        const float* __restrict__ scores,
        const float* __restrict__ ws_vg, const float* __restrict__ ws_d0,
        const float* __restrict__ latent, const float* __restrict__ bo,
        const float* __restrict__ ln2_g, const float* __restrict__ ln2_b,
        const float* __restrict__ fb1, const float* __restrict__ fb2,
        const unsigned short* __restrict__ WoT, const unsigned short* __restrict__ fW1T,
        const unsigned short* __restrict__ fW2T,
        float* __restrict__ xout, float* __restrict__ zout) {
    __shared__ unsigned short s_a[16][136];   // 16 real rows now (attn out, then h1)
    __shared__ unsigned short s_a2[16][136];  // LN2 out, 16 real rows
    __shared__ float s_z[16][128];
    __shared__ float s_lat[128], s_g2[128], s_b2[128], s_fb1v[128], s_fb2v[128];
    int t = threadIdx.x;
    int l = t & 63;
    int w = t >> 6;
    int h = l >> 3, jp = l & 7;
    int base16 = blockIdx.x * 16;

    if (t < 128) {
        s_lat[t] = latent[t] + bo[t];
        s_g2[t] = ln2_g[t]; s_b2[t] = ln2_b[t];
        s_fb1v[t] = fb1[t]; s_fb2v[t] = fb2[t];
    }

    float mn0 = mm[0], mn1 = mm[1], mx0 = mm[2], mx1 = mm[3];
    float st0 = (mx0 - mn0) / 31.0f, st1 = (mx1 - mn1) / 31.0f;
    float vg0 = ws_vg[2 * l], vg1 = ws_vg[2 * l + 1];
    float ag = ws_d0[h];

    // ---- 4 tokens per wave, unrolled: independent load chains overlap ----
    #pragma unroll
    for (int it = 0; it < 4; ++it) {
        int bm = base16 + w * 4 + it;
        int b = bm >> 10;
        int i0 = (bm & 1023) >> 5, i1 = bm & 31;
        float xg0 = (i0 == 31) ? mx0 : mn0 + i0 * st0;
        float xg1 = (i1 == 31) ? mx1 : mn1 + i1 * st1;
        int craw = cnt[bm];
        int c = min(craw, NP);
        if (craw > NP) {
            // rare: rebuild this cell's first-32-in-order point list (stable order)
            int mycell = bm & 1023;
            const int* cb = cell + b * NN;
            int run = 0;
            for (int ch = 0; ch < NN / 64 && run < NP; ++ch) {
                int n = ch * 64 + l;
                bool match = (cb[n] == mycell);
                unsigned long long mask = __ballot(match);
                if (match) {
                    int rank = run + __popcll(mask & ((1ull << l) - 1ull));
                    if (rank < NP) ptIdx[bm * NP + rank] = n;
                }
                run += __popcll(mask);
            }
        }

        int idxreg = 0; float x0r = 0.f, x1r = 0.f;
        if (l < c) {
            idxreg = ptIdx[bm * NP + l];
            float2 xv = ((const float2*)x)[(size_t)b * NN + idxreg];
            x0r = xv.x; x1r = xv.y;
        }

        // score gather: lane (h,jp) takes keys jp, 8+jp, 16+jp, 24+jp
        float areg[4];
        areg[0] = areg[1] = areg[2] = areg[3] = -1e30f;
        #pragma unroll
        for (int g = 0; g < 4; ++g) {
            if (c > g * 8) {               // wave-uniform skip
                int key = g * 8 + jp;
                int idxk = __shfl(idxreg, key);
                if (key < c)
                    areg[g] = scores[((size_t)b * NN + idxk) * 8 + h];
            }
        }
        // v-row prefetch for keys 0..15 (covers c<=16, the common case)
        unsigned vreg[16];
        #pragma unroll
        for (int g = 0; g < 2; ++g) {
            if (c > g * 8) {               // wave-uniform skip
                #pragma unroll
                for (int k8 = 0; k8 < 8; ++k8) {
                    int key = g * 8 + k8;
                    if (key < c) {         // wave-uniform
                        int idxk = __shfl(idxreg, key);
                        vreg[key] = ((const unsigned*)kv)[((size_t)(b * NN + idxk) << 6) + l];
                    }
                }
            }
        }

        // softmax over the per-head score row
        float mx = fmaxf(fmaxf(areg[0], areg[1]), fmaxf(areg[2], areg[3]));
        mx = fmaxf(mx, ag);
        mx = fmaxf(mx, __shfl_xor(mx, 1));
        mx = fmaxf(mx, __shfl_xor(mx, 2));
        mx = fmaxf(mx, __shfl_xor(mx, 4));
        float e0 = __expf(areg[0] - mx), e1 = __expf(areg[1] - mx);
        float e2 = __expf(areg[2] - mx), e3 = __expf(areg[3] - mx);
        float eg = __expf(ag - mx);
        float s = e0 + e1 + e2 + e3;
        s += __shfl_xor(s, 1);
        s += __shfl_xor(s, 2);
        s += __shfl_xor(s, 4);
        s += eg;
        float inv = 1.0f / s;

        // PV: keys 0..15 from registers; keys 16..31 in-loop (rare)
        float accA = eg * inv * vg0, accB = eg * inv * vg1;
        #pragma unroll
        for (int g = 0; g < 2; ++g) {
            if (c > g * 8) {
                float em = (g == 0) ? e0 : e1;
                #pragma unroll
                for (int k8 = 0; k8 < 8; ++k8) {
                    int key = g * 8 + k8;
                    if (key < c) {
                        float a = __shfl(em, (l & 56) | k8) * inv;
                        unsigned vw = vreg[key];
                        accA = fmaf(a, bflo(vw), accA);
                        accB = fmaf(a, bfhi(vw), accB);
                    }
                }
            }
        }
        #pragma unroll
        for (int g = 2; g < 4; ++g) {
            if (c > g * 8) {               // rare: c > 16
                float em = (g == 2) ? e2 : e3;
                #pragma unroll
                for (int k8 = 0; k8 < 8; ++k8) {
                    int key = g * 8 + k8;
                    if (key < c) {
                        int idxk = __shfl(idxreg, key);
                        const unsigned* rowp = (const unsigned*)kv + ((size_t)(b * NN + idxk) << 6);
                        unsigned vw = rowp[l];
                        float a = __shfl(em, (l & 56) | k8) * inv;
                        accA = fmaf(a, bflo(vw), accA);
                        accB = fmaf(a, bfhi(vw), accB);
                    }
                }
            }
        }
        unsigned ow = ((unsigned)f2bf(accB) << 16) | (unsigned)f2bf(accA);
        *(unsigned*)&s_a[w * 4 + it][2 * l] = ow;

        float s0 = e0 * inv, s1 = e1 * inv, s2 = e2 * inv, s3 = e3 * inv, sg = eg * inv;
        #pragma unroll
        for (int m = 8; m <= 32; m <<= 1) {
            s0 += __shfl_xor(s0, m); s1 += __shfl_xor(s1, m);
            s2 += __shfl_xor(s2, m); s3 += __shfl_xor(s3, m);
            sg += __shfl_xor(sg, m);
        }
        float px0 = 0.f, px1 = 0.f;
        {
            float xx0, xx1;
            xx0 = __shfl(x0r, jp);      xx1 = __shfl(x1r, jp);
            px0 = fmaf(s0, xx0, px0);   px1 = fmaf(s0, xx1, px1);
            xx0 = __shfl(x0r, jp + 8);  xx1 = __shfl(x1r, jp + 8);
            px0 = fmaf(s1, xx0, px0);   px1 = fmaf(s1, xx1, px1);
            xx0 = __shfl(x0r, jp + 16); xx1 = __shfl(x1r, jp + 16);
            px0 = fmaf(s2, xx0, px0);   px1 = fmaf(s2, xx1, px1);
            xx0 = __shfl(x0r, jp + 24); xx1 = __shfl(x1r, jp + 24);
            px0 = fmaf(s3, xx0, px0);   px1 = fmaf(s3, xx1, px1);
        }
        px0 += __shfl_xor(px0, 1); px1 += __shfl_xor(px1, 1);
        px0 += __shfl_xor(px0, 2); px1 += __shfl_xor(px1, 2);
        px0 += __shfl_xor(px0, 4); px1 += __shfl_xor(px1, 4);
        if (l == 0) {
            xout[bm * 2]     = (px0 + sg * xg0) * 0.125f;
            xout[bm * 2 + 1] = (px1 + sg * xg1) * 0.125f;
        }
    }

    // ---------------- fused FFN on this block's 16 tokens (M=16, zero padding) ----------------
    __syncthreads();
    int mrow = l & 15, quad = l >> 4;
    { // GEMM1: attn_out @ Wo + (latent + bo) -> s_z rows 0..15
        bf16x8_t a[4];
        #pragma unroll
        for (int kc = 0; kc < 4; ++kc)
            a[kc] = *(const bf16x8_t*)&s_a[mrow][kc * 32 + quad * 8];
        #pragma unroll
        for (int cc = 0; cc < 2; ++cc) {
            int ct = w * 2 + cc;
            f32x4_t acc = {0.f, 0.f, 0.f, 0.f};
            const unsigned short* bp = WoT + (ct * 16 + mrow) * 128 + quad * 8;
            #pragma unroll
            for (int kc = 0; kc < 4; ++kc)
                acc = __builtin_amdgcn_mfma_f32_16x16x32_bf16(a[kc], *(const bf16x8_t*)(bp + kc * 32), acc, 0, 0, 0);
            int f = ct * 16 + mrow;
            #pragma unroll
            for (int r = 0; r < 4; ++r) {
                int row = quad * 4 + r;           // all 16 rows real
                s_z[row][f] = acc[r] + s_lat[f];
            }
        }
    }
    __syncthreads();
    { // LN2: wave w normalizes rows w*4..w*4+3
        #pragma unroll
        for (int i = 0; i < 4; ++i) {
            int row = w * 4 + i;
            float v0 = s_z[row][l], v1 = s_z[row][l + 64];
            float ssum = v0 + v1;
            #pragma unroll
            for (int m = 32; m > 0; m >>= 1) ssum += __shfl_xor(ssum, m);
            float mu = ssum * (1.0f / 128.0f);
            float d0 = v0 - mu, d1 = v1 - mu;
            float qq = d0 * d0 + d1 * d1;
            #pragma unroll
            for (int m = 32; m > 0; m >>= 1) qq += __shfl_xor(qq, m);
            float rstd = rsqrtf(qq * (1.0f / 128.0f) + 1e-5f);
            s_a2[row][l]      = f2bf(d0 * rstd * s_g2[l] + s_b2[l]);
            s_a2[row][l + 64] = f2bf(d1 * rstd * s_g2[l + 64] + s_b2[l + 64]);
        }
    }
    __syncthreads();
    { // GEMM2: relu(LN2 @ fW1 + fb1) -> s_a rows 0..15 (reuse)
        bf16x8_t a[4];
        #pragma unroll
        for (int kc = 0; kc < 4; ++kc)
            a[kc] = *(const bf16x8_t*)&s_a2[mrow][kc * 32 + quad * 8];
        #pragma unroll
        for (int cc = 0; cc < 2; ++cc) {
            int ct = w * 2 + cc;
            f32x4_t acc = {0.f, 0.f, 0.f, 0.f};
            const unsigned short* bp = fW1T + (ct * 16 + mrow) * 128 + quad * 8;
            #pragma unroll
            for (int kc = 0; kc < 4; ++kc)
                acc = __builtin_amdgcn_mfma_f32_16x16x32_bf16(a[kc], *(const bf16x8_t*)(bp + kc * 32), acc, 0, 0, 0);
            int f = ct * 16 + mrow;
            #pragma unroll
            for (int r = 0; r < 4; ++r) {
                int row = quad * 4 + r;
                s_a[row][f] = f2bf(fmaxf(acc[r] + s_fb1v[f], 0.f));
            }
        }
    }
    __syncthreads();
    { // GEMM3: z + h1 @ fW2 + fb2 -> zout (16 real rows)
        bf16x8_t a[4];
        #pragma unroll
        for (int kc = 0; kc < 4; ++kc)
            a[kc] = *(const bf16x8_t*)&s_a[mrow][kc * 32 + quad * 8];
        #pragma unroll
        for (int cc = 0; cc < 2; ++cc) {
            int ct = w * 2 + cc;
            f32x4_t acc = {0.f, 0.f, 0.f, 0.f};
            const unsigned short* bp = fW2T + (ct * 16 + mrow) * 128 + quad * 8;
            #pragma unroll
            for (int kc = 0; kc < 4; ++kc)
                acc = __builtin_amdgcn_mfma_f32_16x16x32_bf16(a[kc], *(const bf16x8_t*)(bp + kc * 32), acc, 0, 0, 0);
            int f = ct * 16 + mrow;
            #pragma unroll
            for (int r = 0; r < 4; ++r) {
                int row = quad * 4 + r;
                zout[(size_t)(base16 + row) * 128 + f] = s_z[row][f] + acc[r] + s_fb2v[f];
            }
        }
    }
}

extern "C" void kernel_launch(void* const* d_in, const int* in_sizes, int n_in,
                              void* d_out, int out_size, void* d_ws, size_t ws_size,
                              hipStream_t stream) {
    const float* x     = (const float*)d_in[0];
    const float* z     = (const float*)d_in[1];
    const float* latent= (const float*)d_in[6];
    const float* Wq    = (const float*)d_in[7];
    const float* Wk    = (const float*)d_in[8];
    const float* Wv    = (const float*)d_in[9];
    const float* Wo    = (const float*)d_in[10];
    const float* bo    = (const float*)d_in[11];
    const float* kW1   = (const float*)d_in[12];
    const float* kb1   = (const float*)d_in[13];
    const float* kW2   = (const float*)d_in[14];
    const float* kb2   = (const float*)d_in[15];
    const float* lnq_g = (const float*)d_in[16];
    const float* lnq_b = (const float*)d_in[17];
    const float* lnk_g = (const float*)d_in[18];
    const float* lnk_b = (const float*)d_in[19];
    const float* ln2_g = (const float*)d_in[20];
    const float* ln2_b = (const float*)d_in[21];
    const float* fW1   = (const float*)d_in[22];
    const float* fb1   = (const float*)d_in[23];
    const float* fW2   = (const float*)d_in[24];
    const float* fb2   = (const float*)d_in[25];

    uint8_t* ws = (uint8_t*)d_ws;
    float* mm     = (float*)(ws + WS_MM);
    float* ws_d0  = (float*)(ws + WS_D0);
    float* ws_q   = (float*)(ws + WS_Q);
    float* ws_vg  = (float*)(ws + WS_VG);
    float4* part  = (float4*)(ws + WS_PART);
    int* cnt      = (int*)(ws + WS_CNT);
    int* cell     = (int*)(ws + WS_CELL);
    int* ptIdx    = (int*)(ws + WS_PIDX);
    unsigned short* WvT  = (unsigned short*)(ws + WS_WVT);
    unsigned short* WoT  = (unsigned short*)(ws + WS_WOT);
    unsigned short* fW1T = (unsigned short*)(ws + WS_FW1T);
    unsigned short* fW2T = (unsigned short*)(ws + WS_FW2T);
    unsigned short* WkqT = (unsigned short*)(ws + WS_WKQT);
    float* scores = (float*)(ws + WS_SCORES);
    unsigned short* kv   = (unsigned short*)(ws + WS_KV);

    float* xout = (float*)d_out;            // [B,32,32,2]  = 16384
    float* zout = (float*)d_out + 16384;    // [B,32,32,128]

    k_setup <<<81,   256, 0, stream>>>(x, Wk, Wv, Wo, fW1, fW2, latent, Wq,
                                       lnq_g, lnq_b, lnk_g, lnk_b, kb1, kW2, kb2,
                                       cnt, WvT, WoT, fW1T, fW2T, ws_q, ws_vg, ws_d0,
                                       WkqT, part);
    k_binkv <<<1280, 256, 0, stream>>>(x, z, part, mm, lnk_g, lnk_b, WkqT,
                                       kW1, kb1, kW2, kb2, WvT, kv, scores,
                                       cell, cnt, ptIdx);
    k_attn  <<<512,  256, 0, stream>>>(x, cell, cnt, ptIdx, mm, kv, scores,
                                       ws_vg, ws_d0,
                                       latent, bo, ln2_g, ln2_b, fb1, fb2,
                                       WoT, fW1T, fW2T, xout, zout);
}